// Round 1
// baseline (356.947 us; speedup 1.0000x reference)
//
#include <hip/hip_runtime.h>
#include <cstdint>
#include <cstddef>

#define B_   8
#define C_   1024
#define L_   1024
#define H_   16
#define CH_  64     // head dim = C/H
#define NG_  32     // groups
#define CPG_ 32     // channels per group

typedef __bf16 bf16;
typedef bf16  bf16x8 __attribute__((ext_vector_type(8)));
typedef bf16  bf16x4 __attribute__((ext_vector_type(4)));
typedef float f32x4  __attribute__((ext_vector_type(4)));

// ---------------------------------------------------------------------------
// async global->LDS, 16B per lane. LDS dest = wave-uniform base + lane*16.
// ---------------------------------------------------------------------------
__device__ __forceinline__ void async_cp16(void* lds, const void* g) {
  __builtin_amdgcn_global_load_lds((__attribute__((address_space(1))) void*)g,
                                   (__attribute__((address_space(3))) void*)lds,
                                   16, 0, 0);
}

// LDS element offset, 32-elem (64B) rows, chunk = 8-elem (16B) unit, XOR swizzle.
// 2-way conflict (free) instead of 8-way for ds_read_b128 of rows.
__device__ __forceinline__ int sw32(int r, int c) {
  return r * 32 + ((c ^ ((r >> 1) & 3)) << 3);
}
// LDS element offset, 64-elem (128B) rows, 8 chunks, XOR swizzle (row&7).
__device__ __forceinline__ int sw64(int r, int c) {
  return r * 64 + ((c ^ (r & 7)) << 3);
}

// ---------------------------------------------------------------------------
// fp32 -> bf16 convert (weights)
// ---------------------------------------------------------------------------
__global__ __launch_bounds__(256) void cvt_bf16_kernel(const float* __restrict__ src,
                                                       bf16* __restrict__ dst, int n4) {
  int i = blockIdx.x * 256 + threadIdx.x;
  if (i < n4) {
    float4 f = reinterpret_cast<const float4*>(src)[i];
    bf16x4 o;
    o[0] = (bf16)f.x; o[1] = (bf16)f.y; o[2] = (bf16)f.z; o[3] = (bf16)f.w;
    reinterpret_cast<bf16x4*>(dst)[i] = o;
  }
}

// ---------------------------------------------------------------------------
// GroupNorm: one block per (b, g). Writes x_norm bf16 (B,C,L) for residual and
// x_norm^T bf16 (B,L,C) via LDS-tiled transpose (coalesced 64B chunks).
// ---------------------------------------------------------------------------
__global__ __launch_bounds__(256) void gn_kernel(const float* __restrict__ x,
                                                 const float* __restrict__ gw,
                                                 const float* __restrict__ gb,
                                                 bf16* __restrict__ xnb,
                                                 bf16* __restrict__ xT) {
  const int b = blockIdx.x >> 5, g = blockIdx.x & 31;
  const int tid = threadIdx.x;
  const float* xs = x + (size_t)(b * C_ + g * CPG_) * L_;

  float s = 0.f, s2 = 0.f;
  for (int i = tid * 4; i < CPG_ * L_; i += 1024) {
    float4 f = *reinterpret_cast<const float4*>(xs + i);
    s  += f.x + f.y + f.z + f.w;
    s2 += f.x * f.x + f.y * f.y + f.z * f.z + f.w * f.w;
  }
  __shared__ float rs[256], rs2[256];
  rs[tid] = s; rs2[tid] = s2;
  __syncthreads();
  for (int d = 128; d > 0; d >>= 1) {
    if (tid < d) { rs[tid] += rs[tid + d]; rs2[tid] += rs2[tid + d]; }
    __syncthreads();
  }
  const float mean = rs[0] * (1.f / 32768.f);
  const float var  = rs2[0] * (1.f / 32768.f) - mean * mean;
  const float inv  = rsqrtf(var + 1e-5f);

  __shared__ float tile[CPG_][257];
  for (int l0 = 0; l0 < L_; l0 += 256) {
    for (int c = 0; c < CPG_; c++) {
      const int gc = g * CPG_ + c;
      const float y = (xs[c * L_ + l0 + tid] - mean) * inv * gw[gc] + gb[gc];
      xnb[(size_t)(b * C_ + gc) * L_ + l0 + tid] = (bf16)y;
      tile[c][tid] = y;
    }
    __syncthreads();
    const int c2 = tid & 31, lw = tid >> 5;
    for (int jj = 0; jj < 32; jj++) {
      const int l = l0 + jj * 8 + lw;
      xT[(size_t)(b * L_ + l) * C_ + g * CPG_ + c2] = (bf16)tile[c2][jj * 8 + lw];
    }
    __syncthreads();
  }
}

// ---------------------------------------------------------------------------
// GEMM mainloop: C[m][n] = sum_k A[m][k] * Bt[n][k].
// 128x128 block tile, BK=32, 4 waves in 2x2, each wave 64x64 (4x4 MFMA tiles).
// global_load_lds(16B) staging, XOR-swizzled LDS layout.
// ---------------------------------------------------------------------------
__device__ __forceinline__ void gemm128_bt(const bf16* __restrict__ A,
                                           const bf16* __restrict__ Bt,
                                           int lda, int ldb, int K,
                                           int m0, int n0,
                                           bf16* As, bf16* Bs,
                                           f32x4 acc[4][4]) {
  const int tid  = threadIdx.x;
  const int wave = tid >> 6, lane = tid & 63;
  const int wm = (wave >> 1) * 64, wn = (wave & 1) * 64;
  const int l4 = lane & 15, quad = lane >> 4;
  const int srow = lane >> 2;                              // staging row within 16
  const int scol = (((lane & 3) ^ ((srow >> 1) & 3)) << 3); // swizzled src chunk

  const bf16* ga = A  + (size_t)(m0 + wave * 16 + srow) * lda + scol;
  const bf16* gb = Bt + (size_t)(n0 + wave * 16 + srow) * ldb + scol;
  bf16* la = As + wave * 16 * 32;
  bf16* lb = Bs + wave * 16 * 32;

  for (int k0 = 0; k0 < K; k0 += 32) {
    __syncthreads();
    async_cp16(la,           ga + k0);
    async_cp16(la + 64 * 32, ga + (size_t)64 * lda + k0);
    async_cp16(lb,           gb + k0);
    async_cp16(lb + 64 * 32, gb + (size_t)64 * ldb + k0);
    __syncthreads();

    bf16x8 af[4], bfv[4];
    #pragma unroll
    for (int i = 0; i < 4; i++) {
      af[i] = *reinterpret_cast<const bf16x8*>(As + sw32(wm + i * 16 + l4, quad));
    }
    #pragma unroll
    for (int j = 0; j < 4; j++) {
      bfv[j] = *reinterpret_cast<const bf16x8*>(Bs + sw32(wn + j * 16 + l4, quad));
    }
    #pragma unroll
    for (int i = 0; i < 4; i++) {
      #pragma unroll
      for (int j = 0; j < 4; j++) {
        acc[i][j] = __builtin_amdgcn_mfma_f32_16x16x32_bf16(af[i], bfv[j], acc[i][j], 0, 0, 0);
      }
    }
  }
}

// ---------------------------------------------------------------------------
// QKV GEMM: A = qkv_w bf16 (3072x1024), Bt = x_norm^T (per batch, 1024x1024).
// Epilogue: +bias, scatter q,k -> (b,h,L,64) [t-major], v -> (b,h,64,L).
// ---------------------------------------------------------------------------
__global__ __launch_bounds__(256) void qkv_gemm_kernel(const bf16* __restrict__ Wq,
                                                       const bf16* __restrict__ xT,
                                                       const float* __restrict__ bias,
                                                       bf16* __restrict__ qT,
                                                       bf16* __restrict__ kT,
                                                       bf16* __restrict__ vB) {
  __shared__ bf16 As[128 * 32], Bs[128 * 32];
  const int bi = blockIdx.z;
  const int m0 = blockIdx.y * 128, n0 = blockIdx.x * 128;

  f32x4 acc[4][4];
  #pragma unroll
  for (int i = 0; i < 4; i++) {
    #pragma unroll
    for (int j = 0; j < 4; j++) { acc[i][j] = (f32x4){0.f, 0.f, 0.f, 0.f}; }
  }

  gemm128_bt(Wq, xT + (size_t)bi * L_ * C_, C_, C_, C_, m0, n0, As, Bs, acc);

  const int tid = threadIdx.x;
  const int wave = tid >> 6, lane = tid & 63;
  const int wm = (wave >> 1) * 64, wn = (wave & 1) * 64;
  const int l4 = lane & 15, quad = lane >> 4;

  #pragma unroll
  for (int i = 0; i < 4; i++) {
    const int ob = m0 + wm + i * 16 + quad * 4;   // rows ob..ob+3 (same head/section)
    const int h = ob / 192, r = ob % 192;
    const int sec = r >> 6, c = r & 63;
    float bb[4];
    #pragma unroll
    for (int rg = 0; rg < 4; rg++) { bb[rg] = bias[ob + rg]; }
    #pragma unroll
    for (int j = 0; j < 4; j++) {
      const int l = n0 + wn + j * 16 + l4;
      f32x4 a = acc[i][j];
      if (sec == 2) {
        #pragma unroll
        for (int rg = 0; rg < 4; rg++) {
          vB[(size_t)((bi * H_ + h) * CH_ + c + rg) * L_ + l] = (bf16)(a[rg] + bb[rg]);
        }
      } else {
        bf16* dst = (sec == 0 ? qT : kT) + (size_t)((bi * H_ + h) * L_ + l) * CH_ + c;
        bf16x4 o;
        #pragma unroll
        for (int rg = 0; rg < 4; rg++) { o[rg] = (bf16)(a[rg] + bb[rg]); }
        *reinterpret_cast<bf16x4*>(dst) = o;
      }
    }
  }
}

// ---------------------------------------------------------------------------
// Flash attention: block = (q-tile of 64, head). 4 waves, 16 t-rows each.
// qT/kT: (head, L, 64) bf16; vB: (head, 64, L) bf16; out aT: (B, L, C) bf16.
// ---------------------------------------------------------------------------
__global__ __launch_bounds__(256) void attn_kernel(const bf16* __restrict__ qT,
                                                   const bf16* __restrict__ kT,
                                                   const bf16* __restrict__ vB,
                                                   bf16* __restrict__ aT) {
  const int hb = blockIdx.y;             // 0..127 = b*16 + h
  const int t0 = blockIdx.x * 64;
  const int tid = threadIdx.x, wave = tid >> 6, lane = tid & 63;
  const int l4 = lane & 15, quad = lane >> 4;
  const bf16* q = qT + (size_t)hb * L_ * CH_;
  const bf16* k = kT + (size_t)hb * L_ * CH_;
  const bf16* v = vB + (size_t)hb * CH_ * L_;

  __shared__ bf16 qs[64 * 64], ks[64 * 64], vs[64 * 64];
  __shared__ bf16 ps[4][16 * 72];        // padded stride 72: conflict-free P xpose

  const int rsub = lane >> 3;
  const int csrc = ((lane & 7) ^ rsub) << 3;   // swizzled source chunk (elems)

  // stage Q tile (rows t0..t0+63, contiguous 8KB)
  {
    const bf16* gq = q + (size_t)t0 * CH_;
    for (int i = wave; i < 8; i += 4) {
      async_cp16((char*)qs + i * 1024, gq + (i * 8 + rsub) * 64 + csrc);
    }
  }
  __syncthreads();
  const bf16x8 aq0 = *reinterpret_cast<const bf16x8*>(qs + sw64(wave * 16 + l4, quad));
  const bf16x8 aq1 = *reinterpret_cast<const bf16x8*>(qs + sw64(wave * 16 + l4, quad + 4));

  f32x4 oacc[4];
  float m_r[4], l_r[4];
  #pragma unroll
  for (int r = 0; r < 4; r++) {
    oacc[r] = (f32x4){0.f, 0.f, 0.f, 0.f};
    m_r[r] = -1e30f; l_r[r] = 0.f;
  }

  for (int s0 = 0; s0 < L_; s0 += 64) {
    __syncthreads();   // prior iter's ks/vs/ps reads done
    {
      const bf16* gk = k + (size_t)s0 * CH_;
      for (int i = wave; i < 8; i += 4) {
        async_cp16((char*)ks + i * 1024, gk + (i * 8 + rsub) * 64 + csrc);
      }
      const bf16* gv = v + s0;           // rows stride L_, 128B segments
      for (int i = wave; i < 8; i += 4) {
        async_cp16((char*)vs + i * 1024, gv + (size_t)(i * 8 + rsub) * L_ + csrc);
      }
    }
    __syncthreads();

    // S = (q kT) for this wave's 16 t-rows x 64 s-cols
    f32x4 st[4];
    #pragma unroll
    for (int j = 0; j < 4; j++) {
      const bf16x8 bk0 = *reinterpret_cast<const bf16x8*>(ks + sw64(j * 16 + l4, quad));
      const bf16x8 bk1 = *reinterpret_cast<const bf16x8*>(ks + sw64(j * 16 + l4, quad + 4));
      f32x4 z = (f32x4){0.f, 0.f, 0.f, 0.f};
      z = __builtin_amdgcn_mfma_f32_16x16x32_bf16(aq0, bk0, z, 0, 0, 0);
      z = __builtin_amdgcn_mfma_f32_16x16x32_bf16(aq1, bk1, z, 0, 0, 0);
      st[j] = z;
    }

    // online softmax (rows = quad*4+reg, spread over 16 lanes within quad)
    float alpha[4];
    #pragma unroll
    for (int r = 0; r < 4; r++) {
      float mx = -1e30f;
      #pragma unroll
      for (int j = 0; j < 4; j++) { st[j][r] *= 0.125f; mx = fmaxf(mx, st[j][r]); }
      #pragma unroll
      for (int d = 1; d < 16; d <<= 1) { mx = fmaxf(mx, __shfl_xor(mx, d)); }
      const float mn = fmaxf(m_r[r], mx);
      alpha[r] = __expf(m_r[r] - mn);
      m_r[r] = mn;
      float sm = 0.f;
      #pragma unroll
      for (int j = 0; j < 4; j++) {
        const float p = __expf(st[j][r] - mn);
        st[j][r] = p; sm += p;
      }
      #pragma unroll
      for (int d = 1; d < 16; d <<= 1) { sm += __shfl_xor(sm, d); }
      l_r[r] = l_r[r] * alpha[r] + sm;
    }

    // P: C-layout -> LDS (padded) -> A-layout
    bf16* pw = ps[wave];
    #pragma unroll
    for (int r = 0; r < 4; r++) {
      #pragma unroll
      for (int j = 0; j < 4; j++) {
        pw[(quad * 4 + r) * 72 + j * 16 + l4] = (bf16)st[j][r];
      }
    }
    #pragma unroll
    for (int ct = 0; ct < 4; ct++) {
      #pragma unroll
      for (int r = 0; r < 4; r++) { oacc[ct][r] *= alpha[r]; }
    }
    __syncthreads();

    const bf16x8 ap0 = *reinterpret_cast<const bf16x8*>(pw + l4 * 72 + quad * 8);
    const bf16x8 ap1 = *reinterpret_cast<const bf16x8*>(pw + l4 * 72 + 32 + quad * 8);
    #pragma unroll
    for (int ct = 0; ct < 4; ct++) {
      const bf16x8 bv0 = *reinterpret_cast<const bf16x8*>(vs + sw64(ct * 16 + l4, quad));
      const bf16x8 bv1 = *reinterpret_cast<const bf16x8*>(vs + sw64(ct * 16 + l4, quad + 4));
      oacc[ct] = __builtin_amdgcn_mfma_f32_16x16x32_bf16(ap0, bv0, oacc[ct], 0, 0, 0);
      oacc[ct] = __builtin_amdgcn_mfma_f32_16x16x32_bf16(ap1, bv1, oacc[ct], 0, 0, 0);
    }
  }

  // epilogue: O / l, write a^T (B, L, C) with head at columns h*64..
  const int bi = hb >> 4, h = hb & 15;
  float linv[4];
  #pragma unroll
  for (int r = 0; r < 4; r++) { linv[r] = 1.f / l_r[r]; }
  #pragma unroll
  for (int ct = 0; ct < 4; ct++) {
    #pragma unroll
    for (int r = 0; r < 4; r++) {
      const int t = t0 + wave * 16 + quad * 4 + r;
      const int c = h * CH_ + ct * 16 + l4;
      aT[(size_t)(bi * L_ + t) * C_ + c] = (bf16)(oacc[ct][r] * linv[r]);
    }
  }
}

// ---------------------------------------------------------------------------
// Proj GEMM + bias + residual: out = x_norm + proj_w @ a + proj_b  (fp32 out)
// ---------------------------------------------------------------------------
__global__ __launch_bounds__(256) void proj_gemm_kernel(const bf16* __restrict__ Wp,
                                                        const bf16* __restrict__ aT,
                                                        const float* __restrict__ bias,
                                                        const bf16* __restrict__ xnb,
                                                        float* __restrict__ out) {
  __shared__ bf16 As[128 * 32], Bs[128 * 32];
  const int bi = blockIdx.z;
  const int m0 = blockIdx.y * 128, n0 = blockIdx.x * 128;

  f32x4 acc[4][4];
  #pragma unroll
  for (int i = 0; i < 4; i++) {
    #pragma unroll
    for (int j = 0; j < 4; j++) { acc[i][j] = (f32x4){0.f, 0.f, 0.f, 0.f}; }
  }

  gemm128_bt(Wp, aT + (size_t)bi * L_ * C_, C_, C_, C_, m0, n0, As, Bs, acc);

  const int tid = threadIdx.x;
  const int wave = tid >> 6, lane = tid & 63;
  const int wm = (wave >> 1) * 64, wn = (wave & 1) * 64;
  const int l4 = lane & 15, quad = lane >> 4;

  #pragma unroll
  for (int i = 0; i < 4; i++) {
    const int ob = m0 + wm + i * 16 + quad * 4;
    float bb[4];
    #pragma unroll
    for (int rg = 0; rg < 4; rg++) { bb[rg] = bias[ob + rg]; }
    #pragma unroll
    for (int j = 0; j < 4; j++) {
      const int l = n0 + wn + j * 16 + l4;
      #pragma unroll
      for (int rg = 0; rg < 4; rg++) {
        const size_t idx = (size_t)(bi * C_ + ob + rg) * L_ + l;
        out[idx] = acc[i][j][rg] + bb[rg] + (float)xnb[idx];
      }
    }
  }
}

// ---------------------------------------------------------------------------
extern "C" void kernel_launch(void* const* d_in, const int* in_sizes, int n_in,
                              void* d_out, int out_size, void* d_ws, size_t ws_size,
                              hipStream_t stream) {
  (void)in_sizes; (void)n_in; (void)out_size; (void)ws_size;
  const float* x      = (const float*)d_in[0];
  const float* norm_w = (const float*)d_in[1];
  const float* norm_b = (const float*)d_in[2];
  const float* qkv_w  = (const float*)d_in[3];
  const float* qkv_b  = (const float*)d_in[4];
  const float* proj_w = (const float*)d_in[5];
  const float* proj_b = (const float*)d_in[6];
  float* out = (float*)d_out;

  char* w = (char*)d_ws;
  auto alloc = [&](size_t bytes) {
    char* p = w;
    w += (bytes + 255) & ~(size_t)255;
    return p;
  };
  bf16* xnb = (bf16*)alloc((size_t)B_ * C_ * L_ * 2);       // x_norm (B,C,L)
  bf16* xT  = (bf16*)alloc((size_t)B_ * L_ * C_ * 2);       // x_norm^T (B,L,C)
  bf16* wq  = (bf16*)alloc((size_t)3 * C_ * C_ * 2);        // qkv_w bf16
  bf16* wp  = (bf16*)alloc((size_t)C_ * C_ * 2);            // proj_w bf16
  bf16* qT  = (bf16*)alloc((size_t)B_ * H_ * L_ * CH_ * 2); // q (b,h,L,64)
  bf16* kT  = (bf16*)alloc((size_t)B_ * H_ * L_ * CH_ * 2); // k (b,h,L,64)
  bf16* vB  = (bf16*)alloc((size_t)B_ * H_ * CH_ * L_ * 2); // v (b,h,64,L)
  bf16* aTb = (bf16*)alloc((size_t)B_ * L_ * C_ * 2);       // a^T (B,L,C)

  cvt_bf16_kernel<<<(3 * C_ * C_ / 4) / 256, 256, 0, stream>>>(qkv_w, wq, 3 * C_ * C_ / 4);
  cvt_bf16_kernel<<<(C_ * C_ / 4) / 256, 256, 0, stream>>>(proj_w, wp, C_ * C_ / 4);
  gn_kernel<<<B_ * NG_, 256, 0, stream>>>(x, norm_w, norm_b, xnb, xT);
  qkv_gemm_kernel<<<dim3(L_ / 128, 3 * C_ / 128, B_), 256, 0, stream>>>(wq, xT, qkv_b, qT, kT, vB);
  attn_kernel<<<dim3(L_ / 64, B_ * H_), 256, 0, stream>>>(qT, kT, vB, aTb);
  proj_gemm_kernel<<<dim3(L_ / 128, C_ / 128, B_), 256, 0, stream>>>(wp, aTb, proj_b, xnb, out);
}

// Round 2
// 333.729 us; speedup vs baseline: 1.0696x; 1.0696x over previous
//
#include <hip/hip_runtime.h>
#include <cstdint>
#include <cstddef>

#define B_   8
#define C_   1024
#define L_   1024
#define H_   16
#define CH_  64     // head dim = C/H
#define NG_  32     // groups
#define CPG_ 32     // channels per group

typedef __bf16 bf16;
typedef _Float16 f16;
typedef bf16  bf16x8 __attribute__((ext_vector_type(8)));
typedef bf16  bf16x4 __attribute__((ext_vector_type(4)));
typedef f16   f16x4  __attribute__((ext_vector_type(4)));
typedef float f32x4  __attribute__((ext_vector_type(4)));

// log2(e)/8 : folds the attention scale (1/8) AND the exp->exp2 conversion into q
#define QSCALE 0.1803368801111203f

// ---------------------------------------------------------------------------
// async global->LDS, 16B per lane. LDS dest = wave-uniform base + lane*16.
// ---------------------------------------------------------------------------
__device__ __forceinline__ void async_cp16(void* lds, const void* g) {
  __builtin_amdgcn_global_load_lds((__attribute__((address_space(1))) void*)g,
                                   (__attribute__((address_space(3))) void*)lds,
                                   16, 0, 0);
}

// LDS element offset, 32-elem (64B) rows, chunk = 8-elem (16B) unit, XOR swizzle.
__device__ __forceinline__ int sw32(int r, int c) {
  return r * 32 + ((c ^ ((r >> 1) & 3)) << 3);
}
// LDS element offset, 64-elem (128B) rows, 8 chunks, XOR swizzle (row&7).
__device__ __forceinline__ int sw64(int r, int c) {
  return r * 64 + ((c ^ (r & 7)) << 3);
}

// ---------------------------------------------------------------------------
// fp32 -> bf16 convert (weights)
// ---------------------------------------------------------------------------
__global__ __launch_bounds__(256) void cvt_bf16_kernel(const float* __restrict__ src,
                                                       bf16* __restrict__ dst, int n4) {
  int i = blockIdx.x * 256 + threadIdx.x;
  if (i < n4) {
    float4 f = reinterpret_cast<const float4*>(src)[i];
    bf16x4 o;
    o[0] = (bf16)f.x; o[1] = (bf16)f.y; o[2] = (bf16)f.z; o[3] = (bf16)f.w;
    reinterpret_cast<bf16x4*>(dst)[i] = o;
  }
}

// ---------------------------------------------------------------------------
// GroupNorm: one block per (b, g). Writes x_norm bf16 (B,C,L) for residual and
// x_norm^T bf16 (B,L,C) via LDS-tiled transpose (coalesced 64B chunks).
// ---------------------------------------------------------------------------
__global__ __launch_bounds__(256) void gn_kernel(const float* __restrict__ x,
                                                 const float* __restrict__ gw,
                                                 const float* __restrict__ gb,
                                                 bf16* __restrict__ xnb,
                                                 bf16* __restrict__ xT) {
  const int b = blockIdx.x >> 5, g = blockIdx.x & 31;
  const int tid = threadIdx.x;
  const float* xs = x + (size_t)(b * C_ + g * CPG_) * L_;

  float s = 0.f, s2 = 0.f;
  for (int i = tid * 4; i < CPG_ * L_; i += 1024) {
    float4 f = *reinterpret_cast<const float4*>(xs + i);
    s  += f.x + f.y + f.z + f.w;
    s2 += f.x * f.x + f.y * f.y + f.z * f.z + f.w * f.w;
  }
  __shared__ float rs[256], rs2[256];
  rs[tid] = s; rs2[tid] = s2;
  __syncthreads();
  for (int d = 128; d > 0; d >>= 1) {
    if (tid < d) { rs[tid] += rs[tid + d]; rs2[tid] += rs2[tid + d]; }
    __syncthreads();
  }
  const float mean = rs[0] * (1.f / 32768.f);
  const float var  = rs2[0] * (1.f / 32768.f) - mean * mean;
  const float inv  = rsqrtf(var + 1e-5f);

  __shared__ float tile[CPG_][257];
  for (int l0 = 0; l0 < L_; l0 += 256) {
    for (int c = 0; c < CPG_; c++) {
      const int gc = g * CPG_ + c;
      const float y = (xs[c * L_ + l0 + tid] - mean) * inv * gw[gc] + gb[gc];
      xnb[(size_t)(b * C_ + gc) * L_ + l0 + tid] = (bf16)y;
      tile[c][tid] = y;
    }
    __syncthreads();
    const int c2 = tid & 31, lw = tid >> 5;
    for (int jj = 0; jj < 32; jj++) {
      const int l = l0 + jj * 8 + lw;
      xT[(size_t)(b * L_ + l) * C_ + g * CPG_ + c2] = (bf16)tile[c2][jj * 8 + lw];
    }
    __syncthreads();
  }
}

// ---------------------------------------------------------------------------
// GEMM mainloop: C[m][n] = sum_k A[m][k] * Bt[n][k].
// 128x128 block tile, BK=32, 4 waves in 2x2, each wave 64x64 (4x4 MFMA tiles).
// global_load_lds(16B) staging, XOR-swizzled LDS layout.
// ---------------------------------------------------------------------------
__device__ __forceinline__ void gemm128_bt(const bf16* __restrict__ A,
                                           const bf16* __restrict__ Bt,
                                           int lda, int ldb, int K,
                                           int m0, int n0,
                                           bf16* As, bf16* Bs,
                                           f32x4 acc[4][4]) {
  const int tid  = threadIdx.x;
  const int wave = tid >> 6, lane = tid & 63;
  const int wm = (wave >> 1) * 64, wn = (wave & 1) * 64;
  const int l4 = lane & 15, quad = lane >> 4;
  const int srow = lane >> 2;                              // staging row within 16
  const int scol = (((lane & 3) ^ ((srow >> 1) & 3)) << 3); // swizzled src chunk

  const bf16* ga = A  + (size_t)(m0 + wave * 16 + srow) * lda + scol;
  const bf16* gb = Bt + (size_t)(n0 + wave * 16 + srow) * ldb + scol;
  bf16* la = As + wave * 16 * 32;
  bf16* lb = Bs + wave * 16 * 32;

  for (int k0 = 0; k0 < K; k0 += 32) {
    __syncthreads();
    async_cp16(la,           ga + k0);
    async_cp16(la + 64 * 32, ga + (size_t)64 * lda + k0);
    async_cp16(lb,           gb + k0);
    async_cp16(lb + 64 * 32, gb + (size_t)64 * ldb + k0);
    __syncthreads();

    bf16x8 af[4], bfv[4];
    #pragma unroll
    for (int i = 0; i < 4; i++) {
      af[i] = *reinterpret_cast<const bf16x8*>(As + sw32(wm + i * 16 + l4, quad));
    }
    #pragma unroll
    for (int j = 0; j < 4; j++) {
      bfv[j] = *reinterpret_cast<const bf16x8*>(Bs + sw32(wn + j * 16 + l4, quad));
    }
    #pragma unroll
    for (int i = 0; i < 4; i++) {
      #pragma unroll
      for (int j = 0; j < 4; j++) {
        acc[i][j] = __builtin_amdgcn_mfma_f32_16x16x32_bf16(af[i], bfv[j], acc[i][j], 0, 0, 0);
      }
    }
  }
}

// ---------------------------------------------------------------------------
// QKV GEMM: A = qkv_w bf16 (3072x1024), Bt = x_norm^T (per batch, 1024x1024).
// Epilogue: +bias; q scaled by log2(e)/8 -> (b,h,L,64); k -> (b,h,L,64);
// v -> fp16 (b,h,64,L).
// ---------------------------------------------------------------------------
__global__ __launch_bounds__(256) void qkv_gemm_kernel(const bf16* __restrict__ Wq,
                                                       const bf16* __restrict__ xT,
                                                       const float* __restrict__ bias,
                                                       bf16* __restrict__ qT,
                                                       bf16* __restrict__ kT,
                                                       f16* __restrict__ vB) {
  __shared__ bf16 As[128 * 32], Bs[128 * 32];
  const int bi = blockIdx.z;
  const int m0 = blockIdx.y * 128, n0 = blockIdx.x * 128;

  f32x4 acc[4][4];
  #pragma unroll
  for (int i = 0; i < 4; i++) {
    #pragma unroll
    for (int j = 0; j < 4; j++) { acc[i][j] = (f32x4){0.f, 0.f, 0.f, 0.f}; }
  }

  gemm128_bt(Wq, xT + (size_t)bi * L_ * C_, C_, C_, C_, m0, n0, As, Bs, acc);

  const int tid = threadIdx.x;
  const int wave = tid >> 6, lane = tid & 63;
  const int wm = (wave >> 1) * 64, wn = (wave & 1) * 64;
  const int l4 = lane & 15, quad = lane >> 4;

  #pragma unroll
  for (int i = 0; i < 4; i++) {
    const int ob = m0 + wm + i * 16 + quad * 4;   // rows ob..ob+3 (same head/section)
    const int h = ob / 192, r = ob % 192;
    const int sec = r >> 6, c = r & 63;
    float bb[4];
    #pragma unroll
    for (int rg = 0; rg < 4; rg++) { bb[rg] = bias[ob + rg]; }
    #pragma unroll
    for (int j = 0; j < 4; j++) {
      const int l = n0 + wn + j * 16 + l4;
      f32x4 a = acc[i][j];
      if (sec == 2) {
        #pragma unroll
        for (int rg = 0; rg < 4; rg++) {
          vB[(size_t)((bi * H_ + h) * CH_ + c + rg) * L_ + l] = (f16)(a[rg] + bb[rg]);
        }
      } else {
        const float sc = (sec == 0) ? QSCALE : 1.0f;
        bf16* dst = (sec == 0 ? qT : kT) + (size_t)((bi * H_ + h) * L_ + l) * CH_ + c;
        bf16x4 o;
        #pragma unroll
        for (int rg = 0; rg < 4; rg++) { o[rg] = (bf16)((a[rg] + bb[rg]) * sc); }
        *reinterpret_cast<bf16x4*>(dst) = o;
      }
    }
  }
}

// ---------------------------------------------------------------------------
// Flash attention, S^T formulation: block = (q-tile of 64, head). 4 waves.
// Computes S^T = K*Q^T so each lane holds 16 s-values of ONE t-row (t = lane&15
// of its wave's 16-t block). The held P values are then directly the A-fragment
// of mfma_f32_16x16x16_f16 for PV -- no LDS round-trip, no lane transpose.
// qT/kT: (head, L, 64) bf16 (q pre-scaled by log2(e)/8); vB: (head, 64, L) f16;
// out aT: (B, L, C) bf16.
// ---------------------------------------------------------------------------
__global__ __launch_bounds__(256) void attn_kernel(const bf16* __restrict__ qT,
                                                   const bf16* __restrict__ kT,
                                                   const f16* __restrict__ vB,
                                                   bf16* __restrict__ aT) {
  const int hb = blockIdx.y;             // 0..127 = b*16 + h
  const int t0 = blockIdx.x * 64;
  const int tid = threadIdx.x, wave = tid >> 6, lane = tid & 63;
  const int l4 = lane & 15, quad = lane >> 4;
  const bf16* q = qT + (size_t)hb * L_ * CH_;
  const bf16* k = kT + (size_t)hb * L_ * CH_;
  const f16*  v = vB + (size_t)hb * CH_ * L_;

  __shared__ bf16 qs[64 * 64], ks[64 * 64];
  __shared__ f16  vs[64 * 64];

  const int rsub = lane >> 3;
  const int csrc = ((lane & 7) ^ rsub) << 3;   // swizzled source chunk (elems)

  // stage Q tile (rows t0..t0+63, contiguous 8KB)
  {
    const bf16* gq = q + (size_t)t0 * CH_;
    for (int i = wave; i < 8; i += 4) {
      async_cp16((char*)qs + i * 1024, gq + (i * 8 + rsub) * 64 + csrc);
    }
  }
  __syncthreads();
  // Q as B-operand: B[k=c=quad*8+j][n=t=l4] -> read qs row (wave*16+l4)
  const bf16x8 bq0 = *reinterpret_cast<const bf16x8*>(qs + sw64(wave * 16 + l4, quad));
  const bf16x8 bq1 = *reinterpret_cast<const bf16x8*>(qs + sw64(wave * 16 + l4, quad + 4));

  f32x4 oacc[4];                 // rows t=quad*4+r, cols c=ct*16+l4
  #pragma unroll
  for (int ct = 0; ct < 4; ct++) { oacc[ct] = (f32x4){0.f, 0.f, 0.f, 0.f}; }
  float m_s = -1e30f, l_s = 0.f; // state for t = (this lane's) l4 row

  for (int s0 = 0; s0 < L_; s0 += 64) {
    __syncthreads();   // prior iter's ks/vs reads done
    {
      const bf16* gk = k + (size_t)s0 * CH_;
      for (int i = wave; i < 8; i += 4) {
        async_cp16((char*)ks + i * 1024, gk + (i * 8 + rsub) * 64 + csrc);
      }
      const f16* gv = v + s0;           // rows stride L_, 128B segments
      for (int i = wave; i < 8; i += 4) {
        async_cp16((char*)vs + i * 1024, gv + (size_t)(i * 8 + rsub) * L_ + csrc);
      }
    }
    __syncthreads();

    // S^T tile: 64 s-rows x 16 t-cols. Lane holds S[s=16j+quad*4+r][t=l4].
    f32x4 st[4];
    #pragma unroll
    for (int j = 0; j < 4; j++) {
      const bf16x8 ak0 = *reinterpret_cast<const bf16x8*>(ks + sw64(j * 16 + l4, quad));
      const bf16x8 ak1 = *reinterpret_cast<const bf16x8*>(ks + sw64(j * 16 + l4, quad + 4));
      f32x4 z = (f32x4){0.f, 0.f, 0.f, 0.f};
      z = __builtin_amdgcn_mfma_f32_16x16x32_bf16(ak0, bq0, z, 0, 0, 0);
      z = __builtin_amdgcn_mfma_f32_16x16x32_bf16(ak1, bq1, z, 0, 0, 0);
      st[j] = z;
    }

    // online softmax in base-2 domain (q pre-scaled by log2(e)/8)
    float mx = -1e30f;
    #pragma unroll
    for (int j = 0; j < 4; j++) {
      #pragma unroll
      for (int r = 0; r < 4; r++) { mx = fmaxf(mx, st[j][r]); }
    }
    mx = fmaxf(mx, __shfl_xor(mx, 16));
    mx = fmaxf(mx, __shfl_xor(mx, 32));
    const float mn = fmaxf(m_s, mx);
    const float alpha = exp2f(m_s - mn);
    m_s = mn;
    float sm = 0.f;
    f16x4 pa[4];
    #pragma unroll
    for (int j = 0; j < 4; j++) {
      #pragma unroll
      for (int r = 0; r < 4; r++) {
        const float p = exp2f(st[j][r] - mn);
        pa[j][r] = (f16)p;
        sm += p;
      }
    }
    sm += __shfl_xor(sm, 16);
    sm += __shfl_xor(sm, 32);
    l_s = l_s * alpha + sm;

    // redistribute alpha from t=l4 (state layout) to t=quad*4+r (oacc rows)
    float ar[4];
    #pragma unroll
    for (int r = 0; r < 4; r++) { ar[r] = __shfl(alpha, quad * 4 + r); }
    #pragma unroll
    for (int ct = 0; ct < 4; ct++) {
      #pragma unroll
      for (int r = 0; r < 4; r++) { oacc[ct][r] *= ar[r]; }
    }

    // PV: O[t][c] += P[t][s] V^T[s][c]; P already in A-frag layout (K=16 chunks)
    #pragma unroll
    for (int ct = 0; ct < 4; ct++) {
      const int c = ct * 16 + l4;
      #pragma unroll
      for (int j = 0; j < 4; j++) {
        const f16x4 vb = *reinterpret_cast<const f16x4*>(
            vs + c * 64 + ((((j << 1) + (quad >> 1)) ^ (c & 7)) << 3) + ((quad & 1) << 2));
        oacc[ct] = __builtin_amdgcn_mfma_f32_16x16x16f16(pa[j], vb, oacc[ct], 0, 0, 0);
      }
    }
  }

  // epilogue: O / l, write a^T (B, L, C) with head at columns h*64..
  const int bi = hb >> 4, h = hb & 15;
  float linv[4];
  #pragma unroll
  for (int r = 0; r < 4; r++) { linv[r] = 1.f / __shfl(l_s, quad * 4 + r); }
  #pragma unroll
  for (int ct = 0; ct < 4; ct++) {
    #pragma unroll
    for (int r = 0; r < 4; r++) {
      const int t = t0 + wave * 16 + quad * 4 + r;
      const int c = h * CH_ + ct * 16 + l4;
      aT[(size_t)(bi * L_ + t) * C_ + c] = (bf16)(oacc[ct][r] * linv[r]);
    }
  }
}

// ---------------------------------------------------------------------------
// Proj GEMM + bias + residual: out = x_norm + proj_w @ a + proj_b  (fp32 out)
// ---------------------------------------------------------------------------
__global__ __launch_bounds__(256) void proj_gemm_kernel(const bf16* __restrict__ Wp,
                                                        const bf16* __restrict__ aT,
                                                        const float* __restrict__ bias,
                                                        const bf16* __restrict__ xnb,
                                                        float* __restrict__ out) {
  __shared__ bf16 As[128 * 32], Bs[128 * 32];
  const int bi = blockIdx.z;
  const int m0 = blockIdx.y * 128, n0 = blockIdx.x * 128;

  f32x4 acc[4][4];
  #pragma unroll
  for (int i = 0; i < 4; i++) {
    #pragma unroll
    for (int j = 0; j < 4; j++) { acc[i][j] = (f32x4){0.f, 0.f, 0.f, 0.f}; }
  }

  gemm128_bt(Wp, aT + (size_t)bi * L_ * C_, C_, C_, C_, m0, n0, As, Bs, acc);

  const int tid = threadIdx.x;
  const int wave = tid >> 6, lane = tid & 63;
  const int wm = (wave >> 1) * 64, wn = (wave & 1) * 64;
  const int l4 = lane & 15, quad = lane >> 4;

  #pragma unroll
  for (int i = 0; i < 4; i++) {
    const int ob = m0 + wm + i * 16 + quad * 4;
    float bb[4];
    #pragma unroll
    for (int rg = 0; rg < 4; rg++) { bb[rg] = bias[ob + rg]; }
    #pragma unroll
    for (int j = 0; j < 4; j++) {
      const int l = n0 + wn + j * 16 + l4;
      #pragma unroll
      for (int rg = 0; rg < 4; rg++) {
        const size_t idx = (size_t)(bi * C_ + ob + rg) * L_ + l;
        out[idx] = acc[i][j][rg] + bb[rg] + (float)xnb[idx];
      }
    }
  }
}

// ---------------------------------------------------------------------------
extern "C" void kernel_launch(void* const* d_in, const int* in_sizes, int n_in,
                              void* d_out, int out_size, void* d_ws, size_t ws_size,
                              hipStream_t stream) {
  (void)in_sizes; (void)n_in; (void)out_size; (void)ws_size;
  const float* x      = (const float*)d_in[0];
  const float* norm_w = (const float*)d_in[1];
  const float* norm_b = (const float*)d_in[2];
  const float* qkv_w  = (const float*)d_in[3];
  const float* qkv_b  = (const float*)d_in[4];
  const float* proj_w = (const float*)d_in[5];
  const float* proj_b = (const float*)d_in[6];
  float* out = (float*)d_out;

  char* w = (char*)d_ws;
  auto alloc = [&](size_t bytes) {
    char* p = w;
    w += (bytes + 255) & ~(size_t)255;
    return p;
  };
  bf16* xnb = (bf16*)alloc((size_t)B_ * C_ * L_ * 2);       // x_norm (B,C,L)
  bf16* xT  = (bf16*)alloc((size_t)B_ * L_ * C_ * 2);       // x_norm^T (B,L,C)
  bf16* wq  = (bf16*)alloc((size_t)3 * C_ * C_ * 2);        // qkv_w bf16
  bf16* wp  = (bf16*)alloc((size_t)C_ * C_ * 2);            // proj_w bf16
  bf16* qT  = (bf16*)alloc((size_t)B_ * H_ * L_ * CH_ * 2); // q (b,h,L,64), pre-scaled
  bf16* kT  = (bf16*)alloc((size_t)B_ * H_ * L_ * CH_ * 2); // k (b,h,L,64)
  f16*  vB  = (f16*)alloc((size_t)B_ * H_ * CH_ * L_ * 2);  // v (b,h,64,L) fp16
  bf16* aTb = (bf16*)alloc((size_t)B_ * L_ * C_ * 2);       // a^T (B,L,C)

  cvt_bf16_kernel<<<(3 * C_ * C_ / 4) / 256, 256, 0, stream>>>(qkv_w, wq, 3 * C_ * C_ / 4);
  cvt_bf16_kernel<<<(C_ * C_ / 4) / 256, 256, 0, stream>>>(proj_w, wp, C_ * C_ / 4);
  gn_kernel<<<B_ * NG_, 256, 0, stream>>>(x, norm_w, norm_b, xnb, xT);
  qkv_gemm_kernel<<<dim3(L_ / 128, 3 * C_ / 128, B_), 256, 0, stream>>>(wq, xT, qkv_b, qT, kT, vB);
  attn_kernel<<<dim3(L_ / 64, B_ * H_), 256, 0, stream>>>(qT, kT, vB, aTb);
  proj_gemm_kernel<<<dim3(L_ / 128, C_ / 128, B_), 256, 0, stream>>>(wp, aTb, proj_b, xnb, out);
}